// Round 9
// baseline (763.944 us; speedup 1.0000x reference)
//
#include <hip/hip_runtime.h>

#define NN 10000
#define NNP 10112  // 79*128 padded rows (slack reads harmless, never stored)
#define NE 320000
#define NG 64
#define D1 128
#define D2 256

typedef unsigned short u16;
typedef short v8s __attribute__((ext_vector_type(8)));
typedef float v4f __attribute__((ext_vector_type(4)));

__device__ __forceinline__ u16 f2bf(float x) {
    unsigned u = __float_as_uint(x);
    return (u16)((u + 0x7fffu + ((u >> 16) & 1u)) >> 16);
}
__device__ __forceinline__ float bf2f(u16 b) {
    return __uint_as_float(((unsigned)b) << 16);
}
__device__ __forceinline__ float sigm(float x) { return 1.f / (1.f + expf(-x)); }

// async global->LDS, 16B per lane; LDS dest = wave-uniform base + lane*16
#define GLDS16(gp, lp)                                                         \
    __builtin_amdgcn_global_load_lds(                                          \
        (__attribute__((address_space(1))) unsigned int*)(unsigned long long)(gp), \
        (__attribute__((address_space(3))) unsigned int*)(lp), 16, 0, 0)

// =====================================================================
// Fused GEMM+GRU (the only GEMM per iteration).
// A = [xs | x]  (row stride S=2C, bf16 hi/lo planes).
// B[4C, 2C]: per channel c (chunk=c/16, m=c%16), rows jp=chunk*64+slot*16+m:
//   slot0 (r):  [Wf_r  | whh_r ]   -> acc j=0 = gi_r + gh_r
//   slot1 (z):  [Wf_z  | whh_z ]   -> acc j=1 = gi_z + gh_z
//   slot2 (ni): [Wf_n  |   0   ]   -> acc j=2 = gi_n
//   slot3 (nh): [  0   | whh_n ]   -> acc j=3 = gh_n
// where Wf = wih @ w[it]^T  (gi = (S x)@w@wih^T = xs@Wf^T).
// r4-proven 128x128 tile, 4 waves 64x64, 16x16x32 mfma, BK=32, 3-term
// split-bf16, single-buffer LDS (dbuf regressed: grid-limited).
// Epilogue: full GRU per lane (c = chunk*16 + (lane&15), gates = acc j),
// h read from A's x region; writes new x bf16 hi/lo at oh/ol
// (double-buffered A -> no read/write race across blocks).
// MODE 0: plain store. MODE 1: relu (layer1->layer2 transition).
// MODE 2: no store, atomicMax monotone-mapped into pool.
// =====================================================================
template<int C, int MODE>
__global__ __launch_bounds__(256)
void ggru_k(const u16* __restrict__ Ah, const u16* __restrict__ Al,
            const u16* __restrict__ Bh, const u16* __restrict__ Bl,
            const float* __restrict__ bih, const float* __restrict__ bhh,
            u16* __restrict__ oh, u16* __restrict__ ol,
            int outS, int outOff,
            const int* __restrict__ batch, unsigned* __restrict__ pool) {
    constexpr int S = 2 * C;  // GEMM K dimension
    __shared__ u16 lds[16384];
    const int tid = threadIdx.x;
    const int wave = tid >> 6, lane = tid & 63;
    const int wm = (wave >> 1) * 64, wn = (wave & 1) * 64;
    const int bm = blockIdx.y * 128, bn = blockIdx.x * 128;
    const int quad = lane >> 4, r16 = lane & 15;

    v4f acc[4][4] = {};
    for (int k0 = 0; k0 < S; k0 += 32) {
#pragma unroll
        for (int j = 0; j < 2; ++j) {
            int row = j * 64 + lane;
            size_t aoff = (size_t)(bm + row) * S + k0 + wave * 8;
            size_t boff = (size_t)(bn + row) * S + k0 + wave * 8;
            int s = (wave * 128 + row) * 8;
            GLDS16(Ah + aoff, &lds[s]);
            GLDS16(Al + aoff, &lds[4096 + s]);
            GLDS16(Bh + boff, &lds[8192 + s]);
            GLDS16(Bl + boff, &lds[12288 + s]);
        }
        __syncthreads();
        v8s ah[4], al[4], bh[4], bl[4];
#pragma unroll
        for (int i = 0; i < 4; ++i) {
            int ra = (quad * 128 + wm + i * 16 + r16) * 8;
            int rb = (quad * 128 + wn + i * 16 + r16) * 8;
            ah[i] = *(const v8s*)&lds[ra];
            al[i] = *(const v8s*)&lds[4096 + ra];
            bh[i] = *(const v8s*)&lds[8192 + rb];
            bl[i] = *(const v8s*)&lds[12288 + rb];
        }
#pragma unroll
        for (int i = 0; i < 4; ++i)
#pragma unroll
            for (int j = 0; j < 4; ++j) {
                acc[i][j] = __builtin_amdgcn_mfma_f32_16x16x32_bf16(ah[i], bh[j], acc[i][j], 0, 0, 0);
                acc[i][j] = __builtin_amdgcn_mfma_f32_16x16x32_bf16(ah[i], bl[j], acc[i][j], 0, 0, 0);
                acc[i][j] = __builtin_amdgcn_mfma_f32_16x16x32_bf16(al[i], bh[j], acc[i][j], 0, 0, 0);
            }
        __syncthreads();
    }

    // epilogue: lane channel c; acc j = {r, z, ni, nh}
    const int chunk = (bn + wn) >> 6;
    const int c = chunk * 16 + r16;
    const float br = bih[c] + bhh[c];
    const float bz = bih[C + c] + bhh[C + c];
    const float bin = bih[2 * C + c];
    const float bhn = bhh[2 * C + c];
#pragma unroll
    for (int i = 0; i < 4; ++i) {
        int R0 = bm + wm + i * 16 + quad * 4;
#pragma unroll
        for (int r = 0; r < 4; ++r) {
            int R = R0 + r;
            if (R >= NN) continue;
            float rr = sigm(acc[i][0][r] + br);
            float zz = sigm(acc[i][1][r] + bz);
            float nn_ = tanhf(acc[i][2][r] + bin + rr * (acc[i][3][r] + bhn));
            size_t hx = (size_t)R * S + C + c;
            float h = bf2f(Ah[hx]) + bf2f(Al[hx]);
            float o = (1.f - zz) * nn_ + zz * h;
            if (MODE == 2) {
                unsigned b = __float_as_uint(o);
                unsigned u = (b & 0x80000000u) ? ~b : (b | 0x80000000u);
                atomicMax(&pool[batch[R] * 256 + c], u);
            } else {
                if (MODE == 1) o = fmaxf(o, 0.f);
                u16 hh = f2bf(o);
                size_t ox = (size_t)R * outS + outOff + c;
                oh[ox] = hh;
                ol[ox] = f2bf(o - bf2f(hh));
            }
        }
    }
}

// =====================================================================
// CSR build
// =====================================================================
__global__ void count_k(const int* __restrict__ dst, int* __restrict__ cnt) {
    int e = blockIdx.x * blockDim.x + threadIdx.x;
    if (e < NE) atomicAdd(&cnt[dst[e]], 1);
}

__global__ void scan_k(const int* __restrict__ cnt, int* __restrict__ off,
                       int* __restrict__ cur) {
    __shared__ int ps[1024];
    const int tid = threadIdx.x;
    const int CH = (NN + 1023) / 1024;
    const int base = tid * CH;
    int s = 0;
    for (int i = 0; i < CH; ++i) {
        int idx = base + i;
        if (idx < NN) s += cnt[idx];
    }
    ps[tid] = s;
    __syncthreads();
    for (int d = 1; d < 1024; d <<= 1) {
        int v = (tid >= d) ? ps[tid - d] : 0;
        __syncthreads();
        ps[tid] += v;
        __syncthreads();
    }
    int run = (tid > 0) ? ps[tid - 1] : 0;
    for (int i = 0; i < CH; ++i) {
        int idx = base + i;
        if (idx <= NN) { off[idx] = run; if (idx < NN) cur[idx] = run; }
        if (idx < NN) run += cnt[idx];
    }
}

__global__ void fill_k(const int* __restrict__ src, const int* __restrict__ dst,
                       int* __restrict__ cur, int* __restrict__ elist) {
    int e = blockIdx.x * blockDim.x + threadIdx.x;
    if (e >= NE) return;
    int p = atomicAdd(&cur[dst[e]], 1);
    elist[p] = src[e];
}

// =====================================================================
// CSR gather on x (bf16 hi/lo): xs[n,:] = sum_{e in in(n)} x[src(e),:]
// Reads x region (cols [C,2C)) of A, writes xs region (cols [0,C)) of
// the SAME buffer (disjoint columns). One wave covers one node's
// channels -> per edge, lanes read contiguous 8B from each plane.
// =====================================================================
template<int C>
__global__ void gather_k(u16* __restrict__ Ah, u16* __restrict__ Al,
                         const int* __restrict__ off, const int* __restrict__ elist) {
    constexpr int S = 2 * C;
    constexpr int LPN = C / 4;
    int t = blockIdx.x * blockDim.x + threadIdx.x;
    int node = t / LPN;
    if (node >= NN) return;
    int c = (t % LPN) * 4;
    int s0 = off[node], s1 = off[node + 1];
    v4f a0 = 0.f, a1 = 0.f, a2 = 0.f, a3 = 0.f;
    auto rd = [&](int e) -> v4f {
        ushort4 hv = *(const ushort4*)(Ah + (size_t)e * S + C + c);
        ushort4 lv = *(const ushort4*)(Al + (size_t)e * S + C + c);
        v4f v;
        v[0] = bf2f(hv.x) + bf2f(lv.x); v[1] = bf2f(hv.y) + bf2f(lv.y);
        v[2] = bf2f(hv.z) + bf2f(lv.z); v[3] = bf2f(hv.w) + bf2f(lv.w);
        return v;
    };
    int i = s0;
    for (; i + 4 <= s1; i += 4) {
        int e0 = elist[i], e1 = elist[i + 1], e2 = elist[i + 2], e3 = elist[i + 3];
        a0 += rd(e0); a1 += rd(e1); a2 += rd(e2); a3 += rd(e3);
    }
    for (; i < s1; ++i) a0 += rd(elist[i]);
    v4f acc = (a0 + a1) + (a2 + a3);
    ushort4 h, l;
    h.x = f2bf(acc[0]); l.x = f2bf(acc[0] - bf2f(h.x));
    h.y = f2bf(acc[1]); l.y = f2bf(acc[1] - bf2f(h.y));
    h.z = f2bf(acc[2]); l.z = f2bf(acc[2] - bf2f(h.z));
    h.w = f2bf(acc[3]); l.w = f2bf(acc[3] - bf2f(h.w));
    *(ushort4*)(Ah + (size_t)node * S + c) = h;
    *(ushort4*)(Al + (size_t)node * S + c) = l;
}

// =====================================================================
// wf_k: Wf = wih @ w[it]^T in fp32.  Wf1[it][j][k] (j<384,k<128),
// Wf2[it][j][k] (j<768,k<256). One thread per output element.
// =====================================================================
__global__ void wf_k(const float* __restrict__ wih1, const float* __restrict__ w1,
                     const float* __restrict__ wih2, const float* __restrict__ w2,
                     float* __restrict__ Wf1, float* __restrict__ Wf2) {
    const int T1 = 3 * 384 * 128;
    const int T2 = 3 * 768 * 256;
    int t = blockIdx.x * blockDim.x + threadIdx.x;
    if (t < T1) {
        int it = t / (384 * 128), rem = t - it * (384 * 128);
        int j = rem / 128, k = rem - j * 128;
        const float4* a = (const float4*)(wih1 + j * 128);
        const float4* b = (const float4*)(w1 + it * 128 * 128 + k * 128);
        float s = 0.f;
        for (int n = 0; n < 32; ++n) {
            float4 av = a[n], bv = b[n];
            s += av.x * bv.x + av.y * bv.y + av.z * bv.z + av.w * bv.w;
        }
        Wf1[t] = s;
        return;
    }
    t -= T1;
    if (t < T2) {
        int it = t / (768 * 256), rem = t - it * (768 * 256);
        int j = rem / 256, k = rem - j * 256;
        const float4* a = (const float4*)(wih2 + j * 256);
        const float4* b = (const float4*)(w2 + it * 256 * 256 + k * 256);
        float s = 0.f;
        for (int n = 0; n < 64; ++n) {
            float4 av = a[n], bv = b[n];
            s += av.x * bv.x + av.y * bv.y + av.z * bv.z + av.w * bv.w;
        }
        Wf2[t] = s;
    }
}

// =====================================================================
// prep_k: assemble B1/B2 (from Wf + whh, slot layout above, bf16 hi/lo)
// + x init into A1[0]'s x region.
// =====================================================================
__global__ void prep_k(const float* __restrict__ Wf1, const float* __restrict__ whh1,
                       const float* __restrict__ Wf2, const float* __restrict__ whh2,
                       const float* __restrict__ xin,
                       u16* __restrict__ B1h, u16* __restrict__ B1l,
                       u16* __restrict__ B2h, u16* __restrict__ B2l,
                       u16* __restrict__ xh, u16* __restrict__ xl) {
    const int NB1 = 3 * 512 * 256;
    const int NB2 = 3 * 1024 * 512;
    int t = blockIdx.x * blockDim.x + threadIdx.x;
    if (t < NB1) {  // B1: [it][jp<512][kk<256], C=128
        int it = t / (512 * 256), rem = t - it * (512 * 256);
        int jp = rem / 256, kk = rem - jp * 256;
        int chunk = jp >> 6, slot = (jp >> 4) & 3, m = jp & 15;
        int c = chunk * 16 + m;
        float v;
        if (kk < 128) {  // xs part: Wf (slot3 -> 0)
            v = (slot < 3) ? Wf1[it * 49152 + (slot * 128 + c) * 128 + kk] : 0.f;
        } else {         // x part: whh (slot2 -> 0)
            int k = kk - 128;
            int g = (slot == 0) ? 0 : (slot == 1) ? 1 : 2;
            v = (slot == 2) ? 0.f : whh1[(g * 128 + c) * 128 + k];
        }
        u16 h = f2bf(v);
        B1h[t] = h; B1l[t] = f2bf(v - bf2f(h));
        return;
    }
    t -= NB1;
    if (t < NB2) {  // B2: [it][jp<1024][kk<512], C=256
        int it = t / (1024 * 512), rem = t - it * (1024 * 512);
        int jp = rem / 512, kk = rem - jp * 512;
        int chunk = jp >> 6, slot = (jp >> 4) & 3, m = jp & 15;
        int c = chunk * 16 + m;
        float v;
        if (kk < 256) {
            v = (slot < 3) ? Wf2[it * 196608 + (slot * 256 + c) * 256 + kk] : 0.f;
        } else {
            int k = kk - 256;
            int g = (slot == 0) ? 0 : (slot == 1) ? 1 : 2;
            v = (slot == 2) ? 0.f : whh2[(g * 256 + c) * 256 + k];
        }
        u16 h = f2bf(v);
        B2h[t] = h; B2l[t] = f2bf(v - bf2f(h));
        return;
    }
    t -= NB2;
    if (t < NN * D1) {  // x init: A1[0].x (stride 256, offset 128)
        int n = t >> 7, c = t & 127;
        float v = xin[t];
        u16 h = f2bf(v);
        xh[n * 256 + 128 + c] = h;
        xl[n * 256 + 128 + c] = f2bf(v - bf2f(h));
    }
}

// zero channels 128..255 of A2[0]'s x region (initial 128->256 pad)
__global__ void pad_k(u16* __restrict__ xh, u16* __restrict__ xl) {
    int t = blockIdx.x * blockDim.x + threadIdx.x;
    if (t >= NN * 128) return;
    int n = t >> 7, c = t & 127;
    size_t o = (size_t)n * 512 + 256 + 128 + c;
    xh[o] = 0;
    xl[o] = 0;
}

__global__ void pool_init_k(unsigned* __restrict__ pool) {
    int t = blockIdx.x * blockDim.x + threadIdx.x;
    if (t < NG * D2) pool[t] = 0x007FFFFFu;  // mapped(-inf)
}

__global__ void fc_k(const unsigned* __restrict__ pool, const float* __restrict__ w,
                     const float* __restrict__ b, float* __restrict__ out) {
    int t = blockIdx.x * blockDim.x + threadIdx.x;
    if (t >= NG * 6) return;
    int g = t / 6, o = t - g * 6;
    float s = b[o];
    for (int c = 0; c < D2; ++c) {
        unsigned u = pool[g * D2 + c];
        unsigned bits = (u & 0x80000000u) ? (u ^ 0x80000000u) : ~u;
        s += __uint_as_float(bits) * w[o * D2 + c];
    }
    out[t] = s;
}

// =======================================================================
extern "C" void kernel_launch(void* const* d_in, const int* in_sizes, int n_in,
                              void* d_out, int out_size, void* d_ws, size_t ws_size,
                              hipStream_t stream) {
    const float* x_in = (const float*)d_in[0];
    const int* ei = (const int*)d_in[1];
    const int* src = ei;
    const int* dst = ei + NE;
    const int* batch = (const int*)d_in[2];
    const float* w1   = (const float*)d_in[3];
    const float* wih1 = (const float*)d_in[4];
    const float* whh1 = (const float*)d_in[5];
    const float* bih1 = (const float*)d_in[6];
    const float* bhh1 = (const float*)d_in[7];
    const float* w2   = (const float*)d_in[8];
    const float* wih2 = (const float*)d_in[9];
    const float* whh2 = (const float*)d_in[10];
    const float* bih2 = (const float*)d_in[11];
    const float* bhh2 = (const float*)d_in[12];
    const float* fcw  = (const float*)d_in[13];
    const float* fcb  = (const float*)d_in[14];
    float* out = (float*)d_out;

    // ---- workspace (~75 MB) ----
    // A buffers hold [xs | x] bf16 hi/lo planes, double-buffered per layer.
    u16* p = (u16*)d_ws;
    u16* A1h[2], *A1l[2], *A2h[2], *A2l[2];
    for (int i = 0; i < 2; ++i) {
        A1h[i] = p; p += NNP * 256;
        A1l[i] = p; p += NNP * 256;
    }
    for (int i = 0; i < 2; ++i) {
        A2h[i] = p; p += NNP * 512;
        A2l[i] = p; p += NNP * 512;
    }
    u16* B1h = p; p += 3 * 512 * 256;
    u16* B1l = p; p += 3 * 512 * 256;
    u16* B2h = p; p += 3 * 1024 * 512;
    u16* B2l = p; p += 3 * 1024 * 512;
    float* Wf1 = (float*)p;                 // [3][384][128]
    float* Wf2 = Wf1 + 3 * 384 * 128;       // [3][768][256]
    int* cnt   = (int*)(Wf2 + 3 * 768 * 256);
    int* off   = cnt + NN;
    int* cur   = off + NN + 1;
    int* elist = cur + NN;
    unsigned* pool = (unsigned*)(elist + NE);

    // ---- CSR + weight prep + pads ----
    hipMemsetAsync(cnt, 0, NN * sizeof(int), stream);
    count_k<<<(NE + 255) / 256, 256, 0, stream>>>(dst, cnt);
    scan_k<<<1, 1024, 0, stream>>>(cnt, off, cur);
    fill_k<<<(NE + 255) / 256, 256, 0, stream>>>(src, dst, cur, elist);
    {
        int total = 3 * 384 * 128 + 3 * 768 * 256;
        wf_k<<<(total + 255) / 256, 256, 0, stream>>>(wih1, w1, wih2, w2, Wf1, Wf2);
    }
    {
        int total = 3 * 512 * 256 + 3 * 1024 * 512 + NN * D1;
        prep_k<<<(total + 255) / 256, 256, 0, stream>>>(
            Wf1, whh1, Wf2, whh2, x_in,
            B1h, B1l, B2h, B2l, A1h[0], A1l[0]);
    }
    pad_k<<<(NN * 128 + 255) / 256, 256, 0, stream>>>(A2h[0], A2l[0]);
    pool_init_k<<<(NG * D2 + 255) / 256, 256, 0, stream>>>(pool);

    const int MT = NNP / 128;  // 79

    // ---------------- layer 1 (C=128, S=256, N=512) ----------------
    // it0: gather(A1[0]) ; ggru A1[0] -> A1[1]
    // it1: gather(A1[1]) ; ggru A1[1] -> A1[0]
    // it2: gather(A1[0]) ; ggru MODE1 -> A2[0].x (relu)
    {
        int gg = (NN * (D1 / 4) + 255) / 256;
        gather_k<D1><<<gg, 256, 0, stream>>>(A1h[0], A1l[0], off, elist);
        ggru_k<D1, 0><<<dim3(4, MT), 256, 0, stream>>>(
            A1h[0], A1l[0], B1h + 0 * 512 * 256, B1l + 0 * 512 * 256,
            bih1, bhh1, A1h[1], A1l[1], 256, 128, nullptr, nullptr);
        gather_k<D1><<<gg, 256, 0, stream>>>(A1h[1], A1l[1], off, elist);
        ggru_k<D1, 0><<<dim3(4, MT), 256, 0, stream>>>(
            A1h[1], A1l[1], B1h + 1 * 512 * 256, B1l + 1 * 512 * 256,
            bih1, bhh1, A1h[0], A1l[0], 256, 128, nullptr, nullptr);
        gather_k<D1><<<gg, 256, 0, stream>>>(A1h[0], A1l[0], off, elist);
        ggru_k<D1, 1><<<dim3(4, MT), 256, 0, stream>>>(
            A1h[0], A1l[0], B1h + 2 * 512 * 256, B1l + 2 * 512 * 256,
            bih1, bhh1, A2h[0], A2l[0], 512, 256, nullptr, nullptr);
    }

    // ---------------- layer 2 (C=256, S=512, N=1024) ----------------
    {
        int gg = (NN * (D2 / 4) + 255) / 256;
        gather_k<D2><<<gg, 256, 0, stream>>>(A2h[0], A2l[0], off, elist);
        ggru_k<D2, 0><<<dim3(8, MT), 256, 0, stream>>>(
            A2h[0], A2l[0], B2h + 0 * 1024 * 512, B2l + 0 * 1024 * 512,
            bih2, bhh2, A2h[1], A2l[1], 512, 256, nullptr, nullptr);
        gather_k<D2><<<gg, 256, 0, stream>>>(A2h[1], A2l[1], off, elist);
        ggru_k<D2, 0><<<dim3(8, MT), 256, 0, stream>>>(
            A2h[1], A2l[1], B2h + 1 * 1024 * 512, B2l + 1 * 1024 * 512,
            bih2, bhh2, A2h[0], A2l[0], 512, 256, nullptr, nullptr);
        gather_k<D2><<<gg, 256, 0, stream>>>(A2h[0], A2l[0], off, elist);
        ggru_k<D2, 2><<<dim3(8, MT), 256, 0, stream>>>(
            A2h[0], A2l[0], B2h + 2 * 1024 * 512, B2l + 2 * 1024 * 512,
            bih2, bhh2, nullptr, nullptr, 0, 0, batch, pool);
    }

    fc_k<<<1, 512, 0, stream>>>(pool, fcw, fcb, out);
}

// Round 10
// 713.625 us; speedup vs baseline: 1.0705x; 1.0705x over previous
//
#include <hip/hip_runtime.h>

#define NN 10000
#define NNP 10112  // 79*128 padded rows (slack reads harmless, never stored)
#define NE 320000
#define NG 64
#define D1 128
#define D2 256
#define MT 79      // row tiles of 128

typedef unsigned short u16;
typedef short v8s __attribute__((ext_vector_type(8)));
typedef float v4f __attribute__((ext_vector_type(4)));

__device__ __forceinline__ u16 f2bf(float x) {
    unsigned u = __float_as_uint(x);
    return (u16)((u + 0x7fffu + ((u >> 16) & 1u)) >> 16);
}
__device__ __forceinline__ float bf2f(u16 b) {
    return __uint_as_float(((unsigned)b) << 16);
}
__device__ __forceinline__ float sigm(float x) { return 1.f / (1.f + expf(-x)); }

// async global->LDS, 16B per lane; LDS dest = wave-uniform base + lane*16
#define GLDS16(gp, lp)                                                         \
    __builtin_amdgcn_global_load_lds(                                          \
        (__attribute__((address_space(1))) unsigned int*)(unsigned long long)(gp), \
        (__attribute__((address_space(3))) unsigned int*)(lp), 16, 0, 0)

// XCD-aware swizzle: 1-D grid of 80*NX blocks. xcd = bid&7 (round-robin HW
// assignment heuristic); each XCD covers row-tile band [xcd*10, xcd*10+10)
// for ALL col tiles -> its A slice + B stay L2-resident (kills the 4-8x
// A refetch seen in r4-r9 FETCH_SIZE).
#define SWIZZLE(bx, by)                          \
    const int bid_ = blockIdx.x;                 \
    const int l_ = bid_ >> 3;                    \
    const int by = (bid_ & 7) * 10 + l_ % 10;    \
    const int bx = l_ / 10;                      \
    if (by >= MT) return;

// =====================================================================
// GEMM1 (r4-proven): D = (Ah+Al)[M,K] @ (Bh+Bl)[4K,K]^T
// B rows [0,K) = w[it]^T -> m: Cm[R*K+gc] ; rows [K,4K) = whh (natural
// gate-major order) -> gh[R*3K + cc] = acc + bhh[cc]  (cc = gc-K).
// 128x128 tile, 4 waves 64x64, 16x16x32 mfma, BK=32, 3-term split-bf16,
// single-buffer LDS (dbuf regressed r5: grid-limited).
// =====================================================================
__global__ __launch_bounds__(256)
void mgh_k(const u16* __restrict__ Ah, const u16* __restrict__ Al,
           const u16* __restrict__ Bh, const u16* __restrict__ Bl,
           const float* __restrict__ bhh, float* __restrict__ Cm,
           float* __restrict__ gh, int K) {
    SWIZZLE(bx, by)
    __shared__ u16 lds[16384];
    const int tid = threadIdx.x;
    const int wave = tid >> 6, lane = tid & 63;
    const int wm = (wave >> 1) * 64, wn = (wave & 1) * 64;
    const int bm = by * 128, bn = bx * 128;
    const int quad = lane >> 4, r16 = lane & 15;

    v4f acc[4][4] = {};
    for (int k0 = 0; k0 < K; k0 += 32) {
#pragma unroll
        for (int j = 0; j < 2; ++j) {
            int row = j * 64 + lane;
            size_t aoff = (size_t)(bm + row) * K + k0 + wave * 8;
            size_t boff = (size_t)(bn + row) * K + k0 + wave * 8;
            int s = (wave * 128 + row) * 8;
            GLDS16(Ah + aoff, &lds[s]);
            GLDS16(Al + aoff, &lds[4096 + s]);
            GLDS16(Bh + boff, &lds[8192 + s]);
            GLDS16(Bl + boff, &lds[12288 + s]);
        }
        __syncthreads();
        v8s ah[4], al[4], bh[4], bl[4];
#pragma unroll
        for (int i = 0; i < 4; ++i) {
            int ra = (quad * 128 + wm + i * 16 + r16) * 8;
            int rb = (quad * 128 + wn + i * 16 + r16) * 8;
            ah[i] = *(const v8s*)&lds[ra];
            al[i] = *(const v8s*)&lds[4096 + ra];
            bh[i] = *(const v8s*)&lds[8192 + rb];
            bl[i] = *(const v8s*)&lds[12288 + rb];
        }
#pragma unroll
        for (int i = 0; i < 4; ++i)
#pragma unroll
            for (int j = 0; j < 4; ++j) {
                acc[i][j] = __builtin_amdgcn_mfma_f32_16x16x32_bf16(ah[i], bh[j], acc[i][j], 0, 0, 0);
                acc[i][j] = __builtin_amdgcn_mfma_f32_16x16x32_bf16(ah[i], bl[j], acc[i][j], 0, 0, 0);
                acc[i][j] = __builtin_amdgcn_mfma_f32_16x16x32_bf16(al[i], bh[j], acc[i][j], 0, 0, 0);
            }
        __syncthreads();
    }

    // epilogue: C/D layout col=lane&15, row=quad*4+reg
#pragma unroll
    for (int i = 0; i < 4; ++i) {
        int gr0 = bm + wm + i * 16 + quad * 4;
#pragma unroll
        for (int j = 0; j < 4; ++j) {
            int gc = bn + wn + j * 16 + r16;
            if (gc < K) {  // m part (block-uniform: K multiple of 128)
#pragma unroll
                for (int r = 0; r < 4; ++r) {
                    int gr = gr0 + r;
                    if (gr < NN) Cm[(size_t)gr * K + gc] = acc[i][j][r];
                }
            } else {       // gh part, natural layout [R][3K]
                int cc = gc - K;
                float bv = bhh[cc];
#pragma unroll
                for (int r = 0; r < 4; ++r) {
                    int gr = gr0 + r;
                    if (gr < NN) gh[(size_t)gr * 3 * K + cc] = acc[i][j][r] + bv;
                }
            }
        }
    }
}

// =====================================================================
// GEMM2 + GRU epilogue. B = wih gate-permuted (verified r7/r8):
// row jp = (c/16)*48 + g*16 + (c%16). Block 128 rows x 96 cols, wave
// 64x48; acc j = gate, all 3 gates of channel c in the SAME lane.
// Epilogue: gi = acc + bih, gh read from natural [R][3C] fp32 (+bhh
// already added), h from x bf16 hi/lo; full GRU; write new x hi/lo.
// In-place x safe: A operand is `a`; x touched only at owned (R,c).
// MODE 0: store stride OS. MODE 1: relu -> stride 256 (layer1->2).
// MODE 2: no store; atomicMax monotone-mapped into pool.
// =====================================================================
template<int MODE, int OS>
__global__ __launch_bounds__(256)
void giqru_k(const u16* __restrict__ Ah, const u16* __restrict__ Al,
             const u16* __restrict__ Bh, const u16* __restrict__ Bl,
             const float* __restrict__ gh, const float* __restrict__ bih,
             const u16* __restrict__ xh_in, const u16* __restrict__ xl_in,
             u16* __restrict__ xh_out, u16* __restrict__ xl_out,
             const int* __restrict__ batch, unsigned* __restrict__ pool,
             int C) {
    SWIZZLE(bx, by)
    __shared__ u16 lds[14336];  // A hi 0, A lo 4096, B hi 8192, B lo 11264
    const int tid = threadIdx.x;
    const int wave = tid >> 6, lane = tid & 63;
    const int wm = (wave >> 1) * 64;   // row half
    const int wn = (wave & 1) * 48;    // col half (16 channels x 3 gates)
    const int bm = by * 128;
    const int bcol = bx * 96;          // permuted B-row base
    const int quad = lane >> 4, r16 = lane & 15;

    v4f acc[4][3] = {};
    for (int k0 = 0; k0 < C; k0 += 32) {
#pragma unroll
        for (int j = 0; j < 2; ++j) {
            int row = j * 64 + lane;
            size_t g = (size_t)(bm + row) * C + k0 + wave * 8;
            int s = (wave * 128 + row) * 8;
            GLDS16(Ah + g, &lds[s]);
            GLDS16(Al + g, &lds[4096 + s]);
        }
        {
            int row = lane;
            size_t g = (size_t)(bcol + row) * C + k0 + wave * 8;
            int s = (wave * 96 + row) * 8;
            GLDS16(Bh + g, &lds[8192 + s]);
            GLDS16(Bl + g, &lds[11264 + s]);
            if (lane < 32) {
                row = 64 + lane;
                g = (size_t)(bcol + row) * C + k0 + wave * 8;
                s = (wave * 96 + row) * 8;
                GLDS16(Bh + g, &lds[8192 + s]);
                GLDS16(Bl + g, &lds[11264 + s]);
            }
        }
        __syncthreads();
        v8s fah[4], fal[4], fbh[3], fbl[3];
#pragma unroll
        for (int i = 0; i < 4; ++i) {
            int ra = (quad * 128 + wm + i * 16 + r16) * 8;
            fah[i] = *(const v8s*)&lds[ra];
            fal[i] = *(const v8s*)&lds[4096 + ra];
        }
#pragma unroll
        for (int g = 0; g < 3; ++g) {
            int rb = (quad * 96 + wn + g * 16 + r16) * 8;
            fbh[g] = *(const v8s*)&lds[8192 + rb];
            fbl[g] = *(const v8s*)&lds[11264 + rb];
        }
#pragma unroll
        for (int i = 0; i < 4; ++i)
#pragma unroll
            for (int g = 0; g < 3; ++g) {
                acc[i][g] = __builtin_amdgcn_mfma_f32_16x16x32_bf16(fah[i], fbh[g], acc[i][g], 0, 0, 0);
                acc[i][g] = __builtin_amdgcn_mfma_f32_16x16x32_bf16(fah[i], fbl[g], acc[i][g], 0, 0, 0);
                acc[i][g] = __builtin_amdgcn_mfma_f32_16x16x32_bf16(fal[i], fbh[g], acc[i][g], 0, 0, 0);
            }
        __syncthreads();
    }

    // epilogue: channel c per lane; gates in acc[.][0..2]
    const int c = (bx * 2 + (wn ? 1 : 0)) * 16 + r16;
    const float bir = bih[c], biz = bih[C + c], bin = bih[2 * C + c];
#pragma unroll
    for (int i = 0; i < 4; ++i) {
        int R0 = bm + wm + i * 16 + quad * 4;
#pragma unroll
        for (int r = 0; r < 4; ++r) {
            int R = R0 + r;
            if (R >= NN) continue;
            const float* gp = gh + (size_t)R * 3 * C + c;
            float ghr = gp[0];
            float ghz = gp[C];
            float ghn = gp[2 * C];
            float rr = sigm(acc[i][0][r] + bir + ghr);
            float zz = sigm(acc[i][1][r] + biz + ghz);
            float nn_ = tanhf(acc[i][2][r] + bin + rr * ghn);
            float h = bf2f(xh_in[(size_t)R * C + c]) + bf2f(xl_in[(size_t)R * C + c]);
            float o = (1.f - zz) * nn_ + zz * h;
            if (MODE == 2) {
                unsigned b = __float_as_uint(o);
                unsigned u = (b & 0x80000000u) ? ~b : (b | 0x80000000u);
                atomicMax(&pool[batch[R] * 256 + c], u);
            } else {
                if (MODE == 1) o = fmaxf(o, 0.f);
                u16 hh = f2bf(o);
                xh_out[(size_t)R * OS + c] = hh;
                xl_out[(size_t)R * OS + c] = f2bf(o - bf2f(hh));
            }
        }
    }
}

// =====================================================================
// CSR build
// =====================================================================
__global__ void count_k(const int* __restrict__ dst, int* __restrict__ cnt) {
    int e = blockIdx.x * blockDim.x + threadIdx.x;
    if (e < NE) atomicAdd(&cnt[dst[e]], 1);
}

__global__ void scan_k(const int* __restrict__ cnt, int* __restrict__ off,
                       int* __restrict__ cur) {
    __shared__ int ps[1024];
    const int tid = threadIdx.x;
    const int CH = (NN + 1023) / 1024;
    const int base = tid * CH;
    int s = 0;
    for (int i = 0; i < CH; ++i) {
        int idx = base + i;
        if (idx < NN) s += cnt[idx];
    }
    ps[tid] = s;
    __syncthreads();
    for (int d = 1; d < 1024; d <<= 1) {
        int v = (tid >= d) ? ps[tid - d] : 0;
        __syncthreads();
        ps[tid] += v;
        __syncthreads();
    }
    int run = (tid > 0) ? ps[tid - 1] : 0;
    for (int i = 0; i < CH; ++i) {
        int idx = base + i;
        if (idx <= NN) { off[idx] = run; if (idx < NN) cur[idx] = run; }
        if (idx < NN) run += cnt[idx];
    }
}

__global__ void fill_k(const int* __restrict__ src, const int* __restrict__ dst,
                       int* __restrict__ cur, int* __restrict__ elist) {
    int e = blockIdx.x * blockDim.x + threadIdx.x;
    if (e >= NE) return;
    int p = atomicAdd(&cur[dst[e]], 1);
    elist[p] = src[e];
}

// =====================================================================
// CSR gather, 4-deep pipeline: a[n,:] = sum m[src,:], bf16 hi/lo out
// =====================================================================
template<int C>
__global__ void gather_k(const float* __restrict__ m, const int* __restrict__ off,
                         const int* __restrict__ elist,
                         u16* __restrict__ ah, u16* __restrict__ al) {
    constexpr int LPN = C / 4;
    int t = blockIdx.x * blockDim.x + threadIdx.x;
    int node = t / LPN;
    if (node >= NN) return;
    int c = (t % LPN) * 4;
    int s0 = off[node], s1 = off[node + 1];
    v4f a0 = 0.f, a1 = 0.f, a2 = 0.f, a3 = 0.f;
    int i = s0;
    for (; i + 4 <= s1; i += 4) {
        int e0 = elist[i], e1 = elist[i + 1], e2 = elist[i + 2], e3 = elist[i + 3];
        v4f v0 = *(const v4f*)(m + (size_t)e0 * C + c);
        v4f v1 = *(const v4f*)(m + (size_t)e1 * C + c);
        v4f v2 = *(const v4f*)(m + (size_t)e2 * C + c);
        v4f v3 = *(const v4f*)(m + (size_t)e3 * C + c);
        a0 += v0; a1 += v1; a2 += v2; a3 += v3;
    }
    for (; i < s1; ++i) {
        int e = elist[i];
        a0 += *(const v4f*)(m + (size_t)e * C + c);
    }
    v4f acc = (a0 + a1) + (a2 + a3);
    ushort4 h, l;
    h.x = f2bf(acc[0]); l.x = f2bf(acc[0] - bf2f(h.x));
    h.y = f2bf(acc[1]); l.y = f2bf(acc[1] - bf2f(h.y));
    h.z = f2bf(acc[2]); l.z = f2bf(acc[2] - bf2f(h.z));
    h.w = f2bf(acc[3]); l.w = f2bf(acc[3] - bf2f(h.w));
    *(ushort4*)(ah + (size_t)node * C + c) = h;
    *(ushort4*)(al + (size_t)node * C + c) = l;
}

// =====================================================================
// prep_k: weight transforms + x init, one launch.
// B1cat[it] [512,128]:  rows 0..127 = w1[it]^T, rows 128..511 = whh1 as-is
// B2cat[it] [1024,256]: rows 0..255 = w2[it]^T, rows 256..1023 = whh2 as-is
// Wi1/Wi2: wih gate-permuted (jp = (c/16)*48 + g*16 + (c%16)).
// =====================================================================
__global__ void prep_k(const float* __restrict__ w1, const float* __restrict__ w2,
                       const float* __restrict__ wih1, const float* __restrict__ whh1,
                       const float* __restrict__ wih2, const float* __restrict__ whh2,
                       const float* __restrict__ xin,
                       u16* __restrict__ B1h, u16* __restrict__ B1l,
                       u16* __restrict__ B2h, u16* __restrict__ B2l,
                       u16* __restrict__ Wi1h, u16* __restrict__ Wi1l,
                       u16* __restrict__ Wi2h, u16* __restrict__ Wi2l,
                       u16* __restrict__ xh, u16* __restrict__ xl) {
    const int n1 = 3 * D1 * D1;  // 49152
    const int n2 = 3 * D2 * D2;  // 196608
    int t = blockIdx.x * blockDim.x + threadIdx.x;
    if (t < n1) {  // w1 transpose -> B1 rows 0..127
        int l = t / (D1 * D1), rem = t - l * (D1 * D1);
        int k = rem / D1, n = rem - k * D1;
        float v = w1[t]; u16 h = f2bf(v);
        int o = (l * 512 + n) * D1 + k;
        B1h[o] = h; B1l[o] = f2bf(v - bf2f(h)); return;
    }
    t -= n1;
    if (t < n1) {  // whh1 as-is, replicate x3 -> B1 rows 128..511
        float v = whh1[t]; u16 h = f2bf(v), lo = f2bf(v - bf2f(h));
        int r = t / D1, k = t - r * D1;
#pragma unroll
        for (int l = 0; l < 3; ++l) {
            int o = (l * 512 + 128 + r) * D1 + k;
            B1h[o] = h; B1l[o] = lo;
        }
        return;
    }
    t -= n1;
    if (t < n2) {  // w2 transpose -> B2 rows 0..255
        int l = t / (D2 * D2), rem = t - l * (D2 * D2);
        int k = rem / D2, n = rem - k * D2;
        float v = w2[t]; u16 h = f2bf(v);
        int o = (l * 1024 + n) * D2 + k;
        B2h[o] = h; B2l[o] = f2bf(v - bf2f(h)); return;
    }
    t -= n2;
    if (t < n2) {  // whh2 as-is, replicate x3 -> B2 rows 256..1023
        float v = whh2[t]; u16 h = f2bf(v), lo = f2bf(v - bf2f(h));
        int r = t / D2, k = t - r * D2;
#pragma unroll
        for (int l = 0; l < 3; ++l) {
            int o = (l * 1024 + 256 + r) * D2 + k;
            B2h[o] = h; B2l[o] = lo;
        }
        return;
    }
    t -= n2;
    if (t < n1) {  // wih1 gate-permute
        int j = t / D1, k = t - j * D1;
        int g = j >> 7, c = j & 127;
        int jp = (c >> 4) * 48 + g * 16 + (c & 15);
        float v = wih1[t]; u16 h = f2bf(v);
        Wi1h[jp * D1 + k] = h; Wi1l[jp * D1 + k] = f2bf(v - bf2f(h)); return;
    }
    t -= n1;
    if (t < n2) {  // wih2 gate-permute
        int j = t / D2, k = t - j * D2;
        int g = j >> 8, c = j & 255;
        int jp = (c >> 4) * 48 + g * 16 + (c & 15);
        float v = wih2[t]; u16 h = f2bf(v);
        Wi2h[jp * D2 + k] = h; Wi2l[jp * D2 + k] = f2bf(v - bf2f(h)); return;
    }
    t -= n2;
    if (t < NN * D1) {  // x init (bf16 hi/lo, stride 128)
        float v = xin[t];
        u16 h = f2bf(v);
        xh[t] = h;
        xl[t] = f2bf(v - bf2f(h));
    }
}

// zero cols 128..255 of the layer-2 x buffer (stride 256)
__global__ void pad_k(u16* __restrict__ xh, u16* __restrict__ xl) {
    int t = blockIdx.x * blockDim.x + threadIdx.x;
    if (t >= NN * 128) return;
    int n = t >> 7, c = 128 + (t & 127);
    xh[n * 256 + c] = 0;
    xl[n * 256 + c] = 0;
}

__global__ void pool_init_k(unsigned* __restrict__ pool) {
    int t = blockIdx.x * blockDim.x + threadIdx.x;
    if (t < NG * D2) pool[t] = 0x007FFFFFu;  // mapped(-inf)
}

__global__ void fc_k(const unsigned* __restrict__ pool, const float* __restrict__ w,
                     const float* __restrict__ b, float* __restrict__ out) {
    int t = blockIdx.x * blockDim.x + threadIdx.x;
    if (t >= NG * 6) return;
    int g = t / 6, o = t - g * 6;
    float s = b[o];
    for (int c = 0; c < D2; ++c) {
        unsigned u = pool[g * D2 + c];
        unsigned bits = (u & 0x80000000u) ? (u ^ 0x80000000u) : ~u;
        s += __uint_as_float(bits) * w[o * D2 + c];
    }
    out[t] = s;
}

// =======================================================================
extern "C" void kernel_launch(void* const* d_in, const int* in_sizes, int n_in,
                              void* d_out, int out_size, void* d_ws, size_t ws_size,
                              hipStream_t stream) {
    const float* x_in = (const float*)d_in[0];
    const int* ei = (const int*)d_in[1];
    const int* src = ei;
    const int* dst = ei + NE;
    const int* batch = (const int*)d_in[2];
    const float* w1   = (const float*)d_in[3];
    const float* wih1 = (const float*)d_in[4];
    const float* whh1 = (const float*)d_in[5];
    const float* bih1 = (const float*)d_in[6];
    const float* bhh1 = (const float*)d_in[7];
    const float* w2   = (const float*)d_in[8];
    const float* wih2 = (const float*)d_in[9];
    const float* whh2 = (const float*)d_in[10];
    const float* bih2 = (const float*)d_in[11];
    const float* bhh2 = (const float*)d_in[12];
    const float* fcw  = (const float*)d_in[13];
    const float* fcb  = (const float*)d_in[14];
    float* out = (float*)d_out;

    // ---- workspace (~75 MB) ----
    float* ws = (float*)d_ws;
    float* mbuf = ws;                          // [NNP,256] fp32 (L1: stride 128)
    float* gh   = mbuf + NNP * 256;            // [NNP,768] fp32 natural layout
    u16* a_h  = (u16*)(gh + (size_t)NNP * 768);// [NNP,256]
    u16* a_l  = a_h + NNP * 256;
    u16* xA_h = a_l + NNP * 256;               // [NNP,128]
    u16* xA_l = xA_h + NNP * 128;
    u16* xB_h = xA_l + NNP * 128;              // [NNP,256]
    u16* xB_l = xB_h + NNP * 256;
    u16* B1h  = xB_l + NNP * 256;              // [3][512][128]
    u16* B1l  = B1h + 3 * 512 * D1;
    u16* B2h  = B1l + 3 * 512 * D1;            // [3][1024][256]
    u16* B2l  = B2h + 3 * 1024 * D2;
    u16* Wi1h = B2l + 3 * 1024 * D2;           // [384,128] permuted
    u16* Wi1l = Wi1h + 3 * D1 * D1;
    u16* Wi2h = Wi1l + 3 * D1 * D1;            // [768,256] permuted
    u16* Wi2l = Wi2h + 3 * D2 * D2;
    int* cnt   = (int*)(Wi2l + 3 * D2 * D2);
    int* off   = cnt + NN;
    int* cur   = off + NN + 1;
    int* elist = cur + NN;
    unsigned* pool = (unsigned*)(elist + NE);

    // ---- CSR + prep + pad + pool init ----
    hipMemsetAsync(cnt, 0, NN * sizeof(int), stream);
    count_k<<<(NE + 255) / 256, 256, 0, stream>>>(dst, cnt);
    scan_k<<<1, 1024, 0, stream>>>(cnt, off, cur);
    fill_k<<<(NE + 255) / 256, 256, 0, stream>>>(src, dst, cur, elist);
    {
        int total = 2 * (3 * D1 * D1) + 2 * (3 * D2 * D2) +
                    (3 * D1 * D1) + (3 * D2 * D2) + NN * D1;
        prep_k<<<(total + 255) / 256, 256, 0, stream>>>(
            w1, w2, wih1, whh1, wih2, whh2, x_in,
            B1h, B1l, B2h, B2l, Wi1h, Wi1l, Wi2h, Wi2l, xA_h, xA_l);
    }
    pad_k<<<(NN * 128 + 255) / 256, 256, 0, stream>>>(xB_h, xB_l);
    pool_init_k<<<(NG * D2 + 255) / 256, 256, 0, stream>>>(pool);

    // swizzled 1-D grids: 80 * NX blocks, NX = C/32 col tiles
    const int G1 = 80 * (D1 / 32);  // 320
    const int G2 = 80 * (D2 / 32);  // 640

    // ---------------- layer 1 (C = 128) ----------------
    for (int it = 0; it < 3; ++it) {
        const int C = D1;
        mgh_k<<<G1, 256, 0, stream>>>(
            xA_h, xA_l, B1h + it * 512 * C, B1l + it * 512 * C,
            bhh1, mbuf, gh, C);
        gather_k<D1><<<(NN * (D1 / 4) + 255) / 256, 256, 0, stream>>>(
            mbuf, off, elist, a_h, a_l);
        if (it < 2)
            giqru_k<0, 128><<<G1, 256, 0, stream>>>(
                a_h, a_l, Wi1h, Wi1l, gh, bih1,
                xA_h, xA_l, xA_h, xA_l, nullptr, nullptr, C);
        else  // relu + write into xB (stride 256; pad cols pre-zeroed)
            giqru_k<1, 256><<<G1, 256, 0, stream>>>(
                a_h, a_l, Wi1h, Wi1l, gh, bih1,
                xA_h, xA_l, xB_h, xB_l, nullptr, nullptr, C);
    }

    // ---------------- layer 2 (C = 256) ----------------
    for (int it = 0; it < 3; ++it) {
        const int C = D2;
        mgh_k<<<G2, 256, 0, stream>>>(
            xB_h, xB_l, B2h + it * 1024 * C, B2l + it * 1024 * C,
            bhh2, mbuf, gh, C);
        gather_k<D2><<<(NN * (D2 / 4) + 255) / 256, 256, 0, stream>>>(
            mbuf, off, elist, a_h, a_l);
        if (it < 2)
            giqru_k<0, 256><<<G2, 256, 0, stream>>>(
                a_h, a_l, Wi2h, Wi2l, gh, bih2,
                xB_h, xB_l, xB_h, xB_l, nullptr, nullptr, C);
        else  // final: fused segment-max pool
            giqru_k<2, 256><<<G2, 256, 0, stream>>>(
                a_h, a_l, Wi2h, Wi2l, gh, bih2,
                xB_h, xB_l, nullptr, nullptr, batch, pool, C);
    }

    fc_k<<<1, 512, 0, stream>>>(pool, fcw, fcb, out);
}